// Round 7
// baseline (68.010 us; speedup 1.0000x reference)
//
#include <hip/hip_runtime.h>

#define F_EPS 1e-4f

constexpr int B = 4, A = 100000, C = 80, M = 32;
constexpr int THREADS = 256;
constexpr int APB = 256;                    // anchors per assign-block
constexpr int BPI = (A + APB - 1) / APB;    // assign blocks per image = 391
constexpr int VPA = C / 4;                  // float4 per anchor row = 20
constexpr int TVI = A * VPA;                // float4 per image = 2,000,000
constexpr int SBX = 512;                    // stream blocks per image
constexpr int SG = SBX * THREADS;           // stream stride = 131072 float4

struct Part { float cls, reg, pos, pad; };

// f(p) = p^2 * (-log(1-p)) on clamped p (natural log). Used by BOTH kernels so
// corrections cancel exactly in fp32 semantics.
__device__ __forceinline__ float fterm(float p) {
  p = fminf(fmaxf(p, F_EPS), 1.0f - F_EPS);
  return p * p * (-__logf(1.0f - p));
}
__device__ __forceinline__ float fquad(float4 v) {
  return (fterm(v.x) + fterm(v.y)) + (fterm(v.z) + fterm(v.w));
}

// ---------------- Kernel 1: per-anchor assignment + corrections ----------------
__global__ __launch_bounds__(THREADS) void focal_assign(
    const float* __restrict__ clsfs,   // [B,A,C]
    const float* __restrict__ rgrss,   // [B,A,4]
    const float* __restrict__ ancs,    // [1,A,4]
    const float* __restrict__ annos,   // [B,M,5]
    Part* __restrict__ part) {         // [B*BPI]
  const int b = blockIdx.x / BPI;
  const int a = (blockIdx.x - b * BPI) * APB + threadIdx.x;
  const int tid = threadIdx.x;

  __shared__ float s_ann[M * 5];
  __shared__ float s_red[3][THREADS / 64];
  if (tid < M * 5) s_ann[tid] = annos[b * M * 5 + tid];
  __syncthreads();

  float reg_acc = 0.0f, corr_acc = 0.0f, pos_acc = 0.0f;

  if (a < A) {
    const float4 anc = ((const float4*)ancs)[a];
    const float ax1 = anc.x, ay1 = anc.y, ax2 = anc.z, ay2 = anc.w;
    const float area_a = (ax2 - ax1) * (ay2 - ay1);
    float maxiou = -2.0f;
    int maxidx = 0;
    #pragma unroll
    for (int m = 0; m < M; ++m) {
      const float bx1 = s_ann[m * 5 + 0], by1 = s_ann[m * 5 + 1];
      const float bx2 = s_ann[m * 5 + 2], by2 = s_ann[m * 5 + 3];
      float iou = -1.0f;
      if (s_ann[m * 5 + 4] != -1.0f) {
        float iw = fmaxf(fminf(ax2, bx2) - fmaxf(ax1, bx1), 0.0f);
        float ih = fmaxf(fminf(ay2, by2) - fmaxf(ay1, by1), 0.0f);
        float inter = iw * ih;
        float area_b = (bx2 - bx1) * (by2 - by1);
        float ua = fmaxf(area_a + area_b - inter, 1e-8f);
        iou = inter / ua;
      }
      if (iou > maxiou) { maxiou = iou; maxidx = m; }
    }
    if (maxiou >= 0.5f) {
      // POSITIVE: one-hot correction at class lbl (baseline counts 0.75*f there)
      const int lbl = (int)s_ann[maxidx * 5 + 4];
      pos_acc = 1.0f;
      float p = clsfs[((size_t)b * A + a) * C + lbl];
      p = fminf(fmaxf(p, F_EPS), 1.0f - F_EPS);
      const float q = 1.0f - p;
      corr_acc = 0.25f * q * q * (-__logf(p)) - 0.75f * p * p * (-__logf(q));
      // regression loss
      const float bx1 = s_ann[maxidx * 5 + 0], by1 = s_ann[maxidx * 5 + 1];
      const float bx2 = s_ann[maxidx * 5 + 2], by2 = s_ann[maxidx * 5 + 3];
      const float ancw = ax2 - ax1, anch = ay2 - ay1;
      const float ancx = ax1 + 0.5f * ancw, ancy = ay1 + 0.5f * anch;
      const float gtw0 = bx2 - bx1, gth0 = by2 - by1;
      const float gtx = bx1 + 0.5f * gtw0, gty = by1 + 0.5f * gth0;
      const float gtw = fmaxf(gtw0, 1.0f), gth = fmaxf(gth0, 1.0f);
      const float t0 = ((gtx - ancx) / ancw) / 0.1f;
      const float t1 = ((gty - ancy) / anch) / 0.1f;
      const float t2 = __logf(gtw / ancw) / 0.2f;
      const float t3 = __logf(gth / anch) / 0.2f;
      const float4 r = ((const float4*)rgrss)[(size_t)b * A + a];
      const float th = 1.0f / 9.0f, hh = 0.5f / 9.0f;
      float d;
      d = fabsf(t0 - r.x); reg_acc += (d <= th) ? 4.5f * d * d : d - hh;
      d = fabsf(t1 - r.y); reg_acc += (d <= th) ? 4.5f * d * d : d - hh;
      d = fabsf(t2 - r.z); reg_acc += (d <= th) ? 4.5f * d * d : d - hh;
      d = fabsf(t3 - r.w); reg_acc += (d <= th) ? 4.5f * d * d : d - hh;
    } else if (!(maxiou < 0.4f)) {
      // IGNORE band [0.4, 0.5): baseline must not count this row at all ->
      // subtract 0.75 * (row sum of f). Rare path; re-reads 80 floats.
      const float4* __restrict__ row =
          (const float4*)(clsfs + ((size_t)b * A + a) * C);
      float s = 0.0f;
      #pragma unroll
      for (int k = 0; k < VPA; ++k) s += fquad(row[k]);
      corr_acc = -0.75f * s;
    }
    // NEGATIVE (maxiou < 0.4): baseline 0.75*f row is exactly right; no work.
  }

  float cls_f = corr_acc, reg_f = reg_acc, pos_f = pos_acc;
  #pragma unroll
  for (int off = 32; off > 0; off >>= 1) {
    cls_f += __shfl_down(cls_f, off);
    reg_f += __shfl_down(reg_f, off);
    pos_f += __shfl_down(pos_f, off);
  }
  const int wave = tid >> 6, lane = tid & 63;
  if (lane == 0) { s_red[0][wave] = cls_f; s_red[1][wave] = reg_f; s_red[2][wave] = pos_f; }
  __syncthreads();
  if (tid == 0) {
    float bc = 0.f, br = 0.f, bp = 0.f;
    #pragma unroll
    for (int v = 0; v < THREADS / 64; ++v) { bc += s_red[0][v]; br += s_red[1][v]; bp += s_red[2][v]; }
    Part q; q.cls = bc; q.reg = br; q.pos = bp; q.pad = 0.f;
    part[blockIdx.x] = q;
  }
}

// ---------------- Kernel 2: pure unweighted streaming sum of f(p) ----------------
__global__ __launch_bounds__(THREADS) void focal_stream(
    const float* __restrict__ clsfs,   // [B,A,C]
    float* __restrict__ part2) {       // [B*SBX]
  const int b = blockIdx.y;
  const float4* __restrict__ base = (const float4*)(clsfs + (size_t)b * A * C);
  const int i0 = blockIdx.x * THREADS + threadIdx.x;

  float a0 = 0.f, a1 = 0.f, a2 = 0.f, a3 = 0.f;

  {
    // batch 1: 8 independent loads in flight, no other memory ops
    const float4 v0 = base[i0];
    const float4 v1 = base[i0 + 1 * SG];
    const float4 v2 = base[i0 + 2 * SG];
    const float4 v3 = base[i0 + 3 * SG];
    const float4 v4 = base[i0 + 4 * SG];
    const float4 v5 = base[i0 + 5 * SG];
    const float4 v6 = base[i0 + 6 * SG];
    const float4 v7 = base[i0 + 7 * SG];
    a0 += fquad(v0);
    a1 += fquad(v1);
    a2 += fquad(v2);
    a3 += fquad(v3);
    a0 += fquad(v4);
    a1 += fquad(v5);
    a2 += fquad(v6);
    a3 += fquad(v7);
  }
  {
    // batch 2: 7 unconditional
    const float4 v0 = base[i0 + 8 * SG];
    const float4 v1 = base[i0 + 9 * SG];
    const float4 v2 = base[i0 + 10 * SG];
    const float4 v3 = base[i0 + 11 * SG];
    const float4 v4 = base[i0 + 12 * SG];
    const float4 v5 = base[i0 + 13 * SG];
    const float4 v6 = base[i0 + 14 * SG];
    a0 += fquad(v0);
    a1 += fquad(v1);
    a2 += fquad(v2);
    a3 += fquad(v3);
    a0 += fquad(v4);
    a1 += fquad(v5);
    a2 += fquad(v6);
  }
  {
    // guarded 16th
    const int i = i0 + 15 * SG;
    if (i < TVI) a3 += fquad(base[i]);
  }

  float cls = (a0 + a1) + (a2 + a3);
  #pragma unroll
  for (int off = 32; off > 0; off >>= 1) cls += __shfl_down(cls, off);

  __shared__ float s_red[THREADS / 64];
  const int wave = threadIdx.x >> 6, lane = threadIdx.x & 63;
  if (lane == 0) s_red[wave] = cls;
  __syncthreads();
  if (threadIdx.x == 0) {
    float bc = 0.f;
    #pragma unroll
    for (int v = 0; v < THREADS / 64; ++v) bc += s_red[v];
    part2[b * SBX + blockIdx.x] = bc;
  }
}

// ---------------- Kernel 3: finalize (wave per image) ----------------
__global__ __launch_bounds__(256) void focal_final(
    const float* __restrict__ annos,
    const Part* __restrict__ part,     // [B*BPI]
    const float* __restrict__ part2,   // [B*SBX]
    float* __restrict__ out) {
  const int tid = threadIdx.x;
  const int wv = tid >> 6, lane = tid & 63;
  __shared__ float s_cls[4], s_reg[4];

  double c = 0.0, r = 0.0, s = 0.0;
  float p = 0.f;
  for (int j = lane; j < BPI; j += 64) {
    const Part q = part[wv * BPI + j];
    c += (double)q.cls; r += (double)q.reg; p += q.pos;
  }
  for (int j = lane; j < SBX; j += 64) s += (double)part2[wv * SBX + j];
  #pragma unroll
  for (int off = 32; off > 0; off >>= 1) {
    c += __shfl_down(c, off);
    r += __shfl_down(r, off);
    s += __shfl_down(s, off);
    p += __shfl_down(p, off);
  }
  const bool valid = (lane < M) && (annos[(wv * M + lane) * 5 + 4] != -1.0f);
  const bool has = __any(valid);
  if (lane == 0) {
    const float pn = p;
    float cls = (float)((0.75 * s + c) / (double)fmaxf(pn, 1.0f));
    float reg = (pn > 0.f) ? (float)(r / ((double)pn * 4.0)) : 0.0f;
    if (!has) { cls = 0.f; reg = 0.f; }
    s_cls[wv] = cls; s_reg[wv] = reg;
  }
  __syncthreads();
  if (tid == 0) {
    out[0] = (s_cls[0] + s_cls[1] + s_cls[2] + s_cls[3]) * 0.25f;
    out[1] = (s_reg[0] + s_reg[1] + s_reg[2] + s_reg[3]) * 0.25f;
  }
}

extern "C" void kernel_launch(void* const* d_in, const int* in_sizes, int n_in,
                              void* d_out, int out_size, void* d_ws, size_t ws_size,
                              hipStream_t stream) {
  const float* clsfs = (const float*)d_in[0];
  const float* rgrss = (const float*)d_in[1];
  const float* ancs  = (const float*)d_in[2];
  const float* annos = (const float*)d_in[3];
  float* out = (float*)d_out;

  // d_ws layout (all regions fully overwritten every call; no memset needed):
  Part*  part  = (Part*)d_ws;                    // B*BPI*16 = 25,024 B
  float* part2 = (float*)((char*)d_ws + 32768);  // B*SBX*4  = 8,192 B

  focal_assign<<<dim3(B * BPI), dim3(THREADS), 0, stream>>>(
      clsfs, rgrss, ancs, annos, part);
  focal_stream<<<dim3(SBX, B), dim3(THREADS), 0, stream>>>(clsfs, part2);
  focal_final<<<1, 256, 0, stream>>>(annos, part, part2, out);
}

// Round 9
// 44.410 us; speedup vs baseline: 1.5314x; 1.5314x over previous
//
#include <hip/hip_runtime.h>

#define F_EPS 1e-4f

constexpr int B = 4, A = 100000, C = 80, M = 32;
constexpr int APB = 256;                    // anchors per block
constexpr int THREADS = 256;
constexpr int VPA = C / 4;                  // float4 per anchor row = 20
constexpr int BPI = (A + APB - 1) / APB;    // blocks per image = 391
constexpr int FPT = APB * VPA / THREADS;    // float4 per thread (full block) = 20

typedef float floatx4 __attribute__((ext_vector_type(4)));   // native vec for nt-load

struct Part { float cls, reg, pos, pad; };  // one per block, no atomics

// f(p) = p^2 * (-log(1-p)); 0.75 negative-path factor applied once at the end.
__device__ __forceinline__ float fterm(float p) {
  p = fminf(fmaxf(p, F_EPS), 1.0f - F_EPS);
  return p * p * (-__logf(1.0f - p));
}
__device__ __forceinline__ float fquadx(floatx4 v) {
  return (fterm(v.x) + fterm(v.y)) + (fterm(v.z) + fterm(v.w));
}

__global__ __launch_bounds__(THREADS) void focal_main(
    const float* __restrict__ clsfs,   // [B,A,C]
    const float* __restrict__ rgrss,   // [B,A,4]
    const float* __restrict__ ancs,    // [1,A,4]
    const float* __restrict__ annos,   // [B,M,5]
    Part* __restrict__ part) {         // [B*BPI]
  const int b = blockIdx.x / BPI;
  const int ablk = blockIdx.x - b * BPI;
  const int a0 = ablk * APB;
  const int tid = threadIdx.x;

  __shared__ float s_ann[M * 5];
  __shared__ float s_w[APB];           // 0 = ignore, 1 = contributes
  __shared__ float s_red[3][THREADS / 64];

  if (tid < M * 5) s_ann[tid] = annos[b * M * 5 + tid];
  __syncthreads();

  float reg_acc = 0.0f, corr_acc = 0.0f, pos_acc = 0.0f;

  // ---- Phase 1: per-anchor IoU argmax, reg loss, one-hot correction ----
  {
    const int a = a0 + tid;
    float wv = 0.0f;
    if (a < A) {
      const float4 anc = ((const float4*)ancs)[a];
      const float ax1 = anc.x, ay1 = anc.y, ax2 = anc.z, ay2 = anc.w;
      const float area_a = (ax2 - ax1) * (ay2 - ay1);
      float maxiou = -2.0f;
      int maxidx = 0;
      #pragma unroll
      for (int m = 0; m < M; ++m) {
        const float bx1 = s_ann[m * 5 + 0], by1 = s_ann[m * 5 + 1];
        const float bx2 = s_ann[m * 5 + 2], by2 = s_ann[m * 5 + 3];
        float iou = -1.0f;
        if (s_ann[m * 5 + 4] != -1.0f) {
          float iw = fmaxf(fminf(ax2, bx2) - fmaxf(ax1, bx1), 0.0f);
          float ih = fmaxf(fminf(ay2, by2) - fmaxf(ay1, by1), 0.0f);
          float inter = iw * ih;
          float area_b = (bx2 - bx1) * (by2 - by1);
          float ua = fmaxf(area_a + area_b - inter, 1e-8f);
          iou = inter / ua;
        }
        if (iou > maxiou) { maxiou = iou; maxidx = m; }
      }
      if (maxiou >= 0.5f) {
        const int lbl = (int)s_ann[maxidx * 5 + 4];
        pos_acc = 1.0f;
        wv = 1.0f;
        // one-hot correction: replace 0.75*f(p) with 0.25*(1-p)^2*(-log p)
        float p = clsfs[((size_t)b * A + a) * C + lbl];
        p = fminf(fmaxf(p, F_EPS), 1.0f - F_EPS);
        const float q = 1.0f - p;
        corr_acc = 0.25f * q * q * (-__logf(p)) - 0.75f * p * p * (-__logf(q));
        // regression loss
        const float bx1 = s_ann[maxidx * 5 + 0], by1 = s_ann[maxidx * 5 + 1];
        const float bx2 = s_ann[maxidx * 5 + 2], by2 = s_ann[maxidx * 5 + 3];
        const float ancw = ax2 - ax1, anch = ay2 - ay1;
        const float ancx = ax1 + 0.5f * ancw, ancy = ay1 + 0.5f * anch;
        const float gtw0 = bx2 - bx1, gth0 = by2 - by1;
        const float gtx = bx1 + 0.5f * gtw0, gty = by1 + 0.5f * gth0;
        const float gtw = fmaxf(gtw0, 1.0f), gth = fmaxf(gth0, 1.0f);
        const float t0 = ((gtx - ancx) / ancw) / 0.1f;
        const float t1 = ((gty - ancy) / anch) / 0.1f;
        const float t2 = __logf(gtw / ancw) / 0.2f;
        const float t3 = __logf(gth / anch) / 0.2f;
        const float4 r = ((const float4*)rgrss)[(size_t)b * A + a];
        const float th = 1.0f / 9.0f, hh = 0.5f / 9.0f;
        float d;
        d = fabsf(t0 - r.x); reg_acc += (d <= th) ? 4.5f * d * d : d - hh;
        d = fabsf(t1 - r.y); reg_acc += (d <= th) ? 4.5f * d * d : d - hh;
        d = fabsf(t2 - r.z); reg_acc += (d <= th) ? 4.5f * d * d : d - hh;
        d = fabsf(t3 - r.w); reg_acc += (d <= th) ? 4.5f * d * d : d - hh;
      } else if (maxiou < 0.4f) {
        wv = 1.0f;   // negative anchor: full f(p) row
      }
    }
    s_w[tid] = wv;
  }
  __syncthreads();

  // ---- Phase 2: branch-free streaming of the [APB x C] slab (non-temporal) ----
  const int nanch = min(APB, A - a0);
  const floatx4* __restrict__ base4 =
      (const floatx4*)(clsfs + ((size_t)b * A + a0) * C);
  float acc0 = 0.f, acc1 = 0.f, acc2 = 0.f, acc3 = 0.f;
  if (nanch == APB) {
    #pragma unroll
    for (int k = 0; k < FPT; k += 4) {
      const int i0 = tid + (k + 0) * THREADS;
      const int i1 = tid + (k + 1) * THREADS;
      const int i2 = tid + (k + 2) * THREADS;
      const int i3 = tid + (k + 3) * THREADS;
      const floatx4 v0 = __builtin_nontemporal_load(base4 + i0);
      const floatx4 v1 = __builtin_nontemporal_load(base4 + i1);
      const floatx4 v2 = __builtin_nontemporal_load(base4 + i2);
      const floatx4 v3 = __builtin_nontemporal_load(base4 + i3);
      const float w0 = s_w[i0 / VPA];
      const float w1 = s_w[i1 / VPA];
      const float w2 = s_w[i2 / VPA];
      const float w3 = s_w[i3 / VPA];
      acc0 += w0 * fquadx(v0);
      acc1 += w1 * fquadx(v1);
      acc2 += w2 * fquadx(v2);
      acc3 += w3 * fquadx(v3);
    }
  } else {
    const int nvec = nanch * VPA;
    for (int i = tid; i < nvec; i += THREADS)
      acc0 += s_w[i / VPA] * fquadx(__builtin_nontemporal_load(base4 + i));
  }
  float cls_acc = 0.75f * ((acc0 + acc1) + (acc2 + acc3)) + corr_acc;

  // ---- Block reduction (registers + LDS, no atomics) ----
  float reg_f = reg_acc, pos_f = pos_acc;
  #pragma unroll
  for (int off = 32; off > 0; off >>= 1) {
    cls_acc += __shfl_down(cls_acc, off);
    reg_f   += __shfl_down(reg_f, off);
    pos_f   += __shfl_down(pos_f, off);
  }
  const int wave = tid >> 6, lane = tid & 63;
  if (lane == 0) { s_red[0][wave] = cls_acc; s_red[1][wave] = reg_f; s_red[2][wave] = pos_f; }
  __syncthreads();
  if (tid == 0) {
    float bc = 0.f, br = 0.f, bp = 0.f;
    #pragma unroll
    for (int v = 0; v < THREADS / 64; ++v) {
      bc += s_red[0][v]; br += s_red[1][v]; bp += s_red[2][v];
    }
    Part q; q.cls = bc; q.reg = br; q.pos = bp; q.pad = 0.f;
    part[blockIdx.x] = q;
  }
}

// ---- Finalize: wave w reduces image w's 391 partials, then mean over B ----
__global__ __launch_bounds__(256) void focal_final(
    const float* __restrict__ annos,
    const Part* __restrict__ part,
    float* __restrict__ out) {
  const int tid = threadIdx.x;
  const int wv = tid >> 6, lane = tid & 63;
  __shared__ float s_cls[4], s_reg[4];

  double c = 0.0, r = 0.0;
  float p = 0.f;
  for (int j = lane; j < BPI; j += 64) {
    const Part q = part[wv * BPI + j];
    c += (double)q.cls; r += (double)q.reg; p += q.pos;
  }
  #pragma unroll
  for (int off = 32; off > 0; off >>= 1) {
    c += __shfl_down(c, off);
    r += __shfl_down(r, off);
    p += __shfl_down(p, off);
  }
  const bool valid = (lane < M) && (annos[(wv * M + lane) * 5 + 4] != -1.0f);
  const bool has = __any(valid);
  if (lane == 0) {
    const float pn = p;
    float cls = (float)(c / (double)fmaxf(pn, 1.0f));
    float reg = (pn > 0.f) ? (float)(r / ((double)pn * 4.0)) : 0.0f;
    if (!has) { cls = 0.f; reg = 0.f; }
    s_cls[wv] = cls; s_reg[wv] = reg;
  }
  __syncthreads();
  if (tid == 0) {
    out[0] = (s_cls[0] + s_cls[1] + s_cls[2] + s_cls[3]) * 0.25f;
    out[1] = (s_reg[0] + s_reg[1] + s_reg[2] + s_reg[3]) * 0.25f;
  }
}

extern "C" void kernel_launch(void* const* d_in, const int* in_sizes, int n_in,
                              void* d_out, int out_size, void* d_ws, size_t ws_size,
                              hipStream_t stream) {
  const float* clsfs = (const float*)d_in[0];
  const float* rgrss = (const float*)d_in[1];
  const float* ancs  = (const float*)d_in[2];
  const float* annos = (const float*)d_in[3];
  float* out = (float*)d_out;
  Part* part = (Part*)d_ws;   // B*BPI*16 = ~25 KB, every slot overwritten each call

  focal_main<<<dim3(B * BPI), dim3(THREADS), 0, stream>>>(
      clsfs, rgrss, ancs, annos, part);
  focal_final<<<1, 256, 0, stream>>>(annos, part, out);
}

// Round 10
// 42.387 us; speedup vs baseline: 1.6045x; 1.0477x over previous
//
#include <hip/hip_runtime.h>

#define F_EPS 1e-4f

constexpr int B = 4, A = 100000, C = 80, M = 32;
constexpr int APB = 256;                    // anchors per block
constexpr int THREADS = 256;
constexpr int VPA = C / 4;                  // float4 per anchor row = 20
constexpr int BPI = (A + APB - 1) / APB;    // blocks per image = 391
constexpr int FPT = APB * VPA / THREADS;    // float4 per thread (full block) = 20

struct Part { float cls, reg, pos, pad; };  // one per block, no atomics

// f(p) = p^2 * (-log(1-p)); 0.75 negative-path factor applied once at the end.
__device__ __forceinline__ float fterm(float p) {
  p = fminf(fmaxf(p, F_EPS), 1.0f - F_EPS);
  return p * p * (-__logf(1.0f - p));
}
__device__ __forceinline__ float fquad(float4 v) {
  return (fterm(v.x) + fterm(v.y)) + (fterm(v.z) + fterm(v.w));
}

__global__ __launch_bounds__(THREADS) void focal_main(
    const float* __restrict__ clsfs,   // [B,A,C]
    const float* __restrict__ rgrss,   // [B,A,4]
    const float* __restrict__ ancs,    // [1,A,4]
    const float* __restrict__ annos,   // [B,M,5]
    Part* __restrict__ part) {         // [B*BPI]
  const int b = blockIdx.x / BPI;
  const int ablk = blockIdx.x - b * BPI;
  const int a0 = ablk * APB;
  const int tid = threadIdx.x;

  __shared__ float s_ann[M * 5];
  __shared__ float s_w[APB];           // 0 = ignore, 1 = contributes
  __shared__ float s_red[3][THREADS / 64];

  if (tid < M * 5) s_ann[tid] = annos[b * M * 5 + tid];
  __syncthreads();

  float reg_acc = 0.0f, corr_acc = 0.0f, pos_acc = 0.0f;

  // ---- Phase 1: per-anchor IoU argmax, reg loss, one-hot correction ----
  {
    const int a = a0 + tid;
    float wv = 0.0f;
    if (a < A) {
      const float4 anc = ((const float4*)ancs)[a];
      const float ax1 = anc.x, ay1 = anc.y, ax2 = anc.z, ay2 = anc.w;
      const float area_a = (ax2 - ax1) * (ay2 - ay1);
      float maxiou = -2.0f;
      int maxidx = 0;
      #pragma unroll
      for (int m = 0; m < M; ++m) {
        const float bx1 = s_ann[m * 5 + 0], by1 = s_ann[m * 5 + 1];
        const float bx2 = s_ann[m * 5 + 2], by2 = s_ann[m * 5 + 3];
        float iou = -1.0f;
        if (s_ann[m * 5 + 4] != -1.0f) {
          float iw = fmaxf(fminf(ax2, bx2) - fmaxf(ax1, bx1), 0.0f);
          float ih = fmaxf(fminf(ay2, by2) - fmaxf(ay1, by1), 0.0f);
          float inter = iw * ih;
          float area_b = (bx2 - bx1) * (by2 - by1);
          float ua = fmaxf(area_a + area_b - inter, 1e-8f);
          iou = inter / ua;
        }
        if (iou > maxiou) { maxiou = iou; maxidx = m; }
      }
      if (maxiou >= 0.5f) {
        const int lbl = (int)s_ann[maxidx * 5 + 4];
        pos_acc = 1.0f;
        wv = 1.0f;
        // one-hot correction: replace 0.75*f(p) with 0.25*(1-p)^2*(-log p)
        float p = clsfs[((size_t)b * A + a) * C + lbl];
        p = fminf(fmaxf(p, F_EPS), 1.0f - F_EPS);
        const float q = 1.0f - p;
        corr_acc = 0.25f * q * q * (-__logf(p)) - 0.75f * p * p * (-__logf(q));
        // regression loss
        const float bx1 = s_ann[maxidx * 5 + 0], by1 = s_ann[maxidx * 5 + 1];
        const float bx2 = s_ann[maxidx * 5 + 2], by2 = s_ann[maxidx * 5 + 3];
        const float ancw = ax2 - ax1, anch = ay2 - ay1;
        const float ancx = ax1 + 0.5f * ancw, ancy = ay1 + 0.5f * anch;
        const float gtw0 = bx2 - bx1, gth0 = by2 - by1;
        const float gtx = bx1 + 0.5f * gtw0, gty = by1 + 0.5f * gth0;
        const float gtw = fmaxf(gtw0, 1.0f), gth = fmaxf(gth0, 1.0f);
        const float t0 = ((gtx - ancx) / ancw) / 0.1f;
        const float t1 = ((gty - ancy) / anch) / 0.1f;
        const float t2 = __logf(gtw / ancw) / 0.2f;
        const float t3 = __logf(gth / anch) / 0.2f;
        const float4 r = ((const float4*)rgrss)[(size_t)b * A + a];
        const float th = 1.0f / 9.0f, hh = 0.5f / 9.0f;
        float d;
        d = fabsf(t0 - r.x); reg_acc += (d <= th) ? 4.5f * d * d : d - hh;
        d = fabsf(t1 - r.y); reg_acc += (d <= th) ? 4.5f * d * d : d - hh;
        d = fabsf(t2 - r.z); reg_acc += (d <= th) ? 4.5f * d * d : d - hh;
        d = fabsf(t3 - r.w); reg_acc += (d <= th) ? 4.5f * d * d : d - hh;
      } else if (maxiou < 0.4f) {
        wv = 1.0f;   // negative anchor: full f(p) row
      }
    }
    s_w[tid] = wv;
  }
  __syncthreads();

  // ---- Phase 2: branch-free streaming of the [APB x C] slab ----
  const int nanch = min(APB, A - a0);
  const float4* __restrict__ base4 =
      (const float4*)(clsfs + ((size_t)b * A + a0) * C);
  float acc0 = 0.f, acc1 = 0.f, acc2 = 0.f, acc3 = 0.f;
  if (nanch == APB) {
    #pragma unroll
    for (int k = 0; k < FPT; k += 4) {
      const int i0 = tid + (k + 0) * THREADS;
      const int i1 = tid + (k + 1) * THREADS;
      const int i2 = tid + (k + 2) * THREADS;
      const int i3 = tid + (k + 3) * THREADS;
      const float4 v0 = base4[i0];
      const float4 v1 = base4[i1];
      const float4 v2 = base4[i2];
      const float4 v3 = base4[i3];
      const float w0 = s_w[i0 / VPA];
      const float w1 = s_w[i1 / VPA];
      const float w2 = s_w[i2 / VPA];
      const float w3 = s_w[i3 / VPA];
      acc0 += w0 * fquad(v0);
      acc1 += w1 * fquad(v1);
      acc2 += w2 * fquad(v2);
      acc3 += w3 * fquad(v3);
    }
  } else {
    const int nvec = nanch * VPA;
    for (int i = tid; i < nvec; i += THREADS)
      acc0 += s_w[i / VPA] * fquad(base4[i]);
  }
  float cls_acc = 0.75f * ((acc0 + acc1) + (acc2 + acc3)) + corr_acc;

  // ---- Block reduction (registers + LDS, no atomics) ----
  float reg_f = reg_acc, pos_f = pos_acc;
  #pragma unroll
  for (int off = 32; off > 0; off >>= 1) {
    cls_acc += __shfl_down(cls_acc, off);
    reg_f   += __shfl_down(reg_f, off);
    pos_f   += __shfl_down(pos_f, off);
  }
  const int wave = tid >> 6, lane = tid & 63;
  if (lane == 0) { s_red[0][wave] = cls_acc; s_red[1][wave] = reg_f; s_red[2][wave] = pos_f; }
  __syncthreads();
  if (tid == 0) {
    float bc = 0.f, br = 0.f, bp = 0.f;
    #pragma unroll
    for (int v = 0; v < THREADS / 64; ++v) {
      bc += s_red[0][v]; br += s_red[1][v]; bp += s_red[2][v];
    }
    Part q; q.cls = bc; q.reg = br; q.pos = bp; q.pad = 0.f;
    part[blockIdx.x] = q;
  }
}

// ---- Finalize: wave w reduces image w's 391 partials, then mean over B ----
__global__ __launch_bounds__(256) void focal_final(
    const float* __restrict__ annos,
    const Part* __restrict__ part,
    float* __restrict__ out) {
  const int tid = threadIdx.x;
  const int wv = tid >> 6, lane = tid & 63;
  __shared__ float s_cls[4], s_reg[4];

  double c = 0.0, r = 0.0;
  float p = 0.f;
  for (int j = lane; j < BPI; j += 64) {
    const Part q = part[wv * BPI + j];
    c += (double)q.cls; r += (double)q.reg; p += q.pos;
  }
  #pragma unroll
  for (int off = 32; off > 0; off >>= 1) {
    c += __shfl_down(c, off);
    r += __shfl_down(r, off);
    p += __shfl_down(p, off);
  }
  const bool valid = (lane < M) && (annos[(wv * M + lane) * 5 + 4] != -1.0f);
  const bool has = __any(valid);
  if (lane == 0) {
    const float pn = p;
    float cls = (float)(c / (double)fmaxf(pn, 1.0f));
    float reg = (pn > 0.f) ? (float)(r / ((double)pn * 4.0)) : 0.0f;
    if (!has) { cls = 0.f; reg = 0.f; }
    s_cls[wv] = cls; s_reg[wv] = reg;
  }
  __syncthreads();
  if (tid == 0) {
    out[0] = (s_cls[0] + s_cls[1] + s_cls[2] + s_cls[3]) * 0.25f;
    out[1] = (s_reg[0] + s_reg[1] + s_reg[2] + s_reg[3]) * 0.25f;
  }
}

extern "C" void kernel_launch(void* const* d_in, const int* in_sizes, int n_in,
                              void* d_out, int out_size, void* d_ws, size_t ws_size,
                              hipStream_t stream) {
  const float* clsfs = (const float*)d_in[0];
  const float* rgrss = (const float*)d_in[1];
  const float* ancs  = (const float*)d_in[2];
  const float* annos = (const float*)d_in[3];
  float* out = (float*)d_out;
  Part* part = (Part*)d_ws;   // B*BPI*16 = ~25 KB, every slot overwritten each call

  focal_main<<<dim3(B * BPI), dim3(THREADS), 0, stream>>>(
      clsfs, rgrss, ancs, annos, part);
  focal_final<<<1, 256, 0, stream>>>(annos, part, out);
}